// Round 12
// baseline (378.297 us; speedup 1.0000x reference)
//
#include <hip/hip_runtime.h>

typedef unsigned short u16;
typedef __attribute__((ext_vector_type(8))) short short8;
typedef __attribute__((ext_vector_type(4))) float f32x4;
typedef __attribute__((ext_vector_type(2))) float f32x2;

#define N_AGENTS 131072
#define HID 128
#define FUT 12
#define OBS 8

constexpr int AG = 8;              // 16-agent tiles per block -> 128 agents/block
#define NEG_K  (-1.4426950408889634f)   // -log2(e)
#define NEG_2K (-2.8853900817779268f)   // -2*log2(e)

__device__ __forceinline__ u16 f2bf(float f) {   // RNE (setup only)
    union { float f; unsigned int i; } v; v.f = f;
    unsigned int u = v.i;
    return (u16)((u + 0x7fffu + ((u >> 16) & 1u)) >> 16);
}
__device__ __forceinline__ float bexp2(float x) {
#if __has_builtin(__builtin_amdgcn_exp2f)
    return __builtin_amdgcn_exp2f(x);
#else
    float r; asm("v_exp_f32 %0, %1" : "=v"(r) : "v"(x)); return r;
#endif
}
__device__ __forceinline__ float brcp(float x) {
#if __has_builtin(__builtin_amdgcn_rcpf)
    return __builtin_amdgcn_rcpf(x);
#else
    float r; asm("v_rcp_f32 %0, %1" : "=v"(r) : "v"(x)); return r;
#endif
}
__device__ __forceinline__ unsigned cvtpk(float lo, float hi) {  // 2x f32 -> packed bf16 (RNE)
    unsigned r; asm("v_cvt_pk_bf16_f32 %0, %1, %2" : "=v"(r) : "v"(lo), "v"(hi)); return r;
}

__launch_bounds__(512, 4)
__global__ void lstm_dec_kernel(const float* __restrict__ obs,
                                const float* __restrict__ h0g,
                                const float* __restrict__ Wih,
                                const float* __restrict__ Whh,
                                const float* __restrict__ bih,
                                const float* __restrict__ bhh,
                                const float* __restrict__ Wout,
                                const float* __restrict__ bout,
                                float* __restrict__ dout)
{
    __shared__ short8 hb[2][16][17];     // h double-buffer, rows padded to 272B
    __shared__ float  xt[16][2];
    __shared__ float  ot[FUT][16][2];    // staged outputs (384 floats)
    __shared__ short8 outb_lds[4][64];   // W_out B-fragments per (kf, lane)

    const int tid  = threadIdx.x;
    const int lane = tid & 63;
    const int wv   = tid >> 6;      // wave 0..7, owns hidden [16*wv, 16*wv+16)
    const int r    = lane & 15;
    const int kb   = lane >> 4;

    const float bout0 = bout[0];    // uniform -> SGPR
    const float bout1 = bout[1];

    // scaled effective bias (added in-cell), 4 VGPR
    float beff[4];
#pragma unroll
    for (int nt = 0; nt < 4; ++nt) {
        const float gs = (nt == 2) ? NEG_2K : NEG_K;
        int c = nt * HID + wv * 16 + r;
        float w0 = Wih[c * 2 + 0];
        float w1 = Wih[c * 2 + 1];
        beff[nt] = (bih[c] + bhh[c] + w0 * bout0 + w1 * bout1) * gs;
    }

    // W_eff = (W_hh + W_ih @ W_out) * gsc  fragments (bf16): 64 VGPR
    short8 bfrag[4][4];
#pragma unroll
    for (int kf = 0; kf < 4; ++kf) {
        const int k0 = kf * 32 + kb * 8;
        float wo0[8], wo1[8];
#pragma unroll
        for (int j = 0; j < 8; ++j) {
            wo0[j] = Wout[0 * HID + k0 + j];
            wo1[j] = Wout[1 * HID + k0 + j];
        }
        if (wv == 0) {   // out-projection B-frag -> LDS
            short8 ob;
#pragma unroll
            for (int j = 0; j < 8; ++j) {
                float sel = (r == 0) ? wo0[j] : ((r == 1) ? wo1[j] : 0.0f);
                ob[j] = (short)f2bf(sel);
            }
            outb_lds[kf][lane] = ob;
        }
#pragma unroll
        for (int nt = 0; nt < 4; ++nt) {
            const float gs = (nt == 2) ? NEG_2K : NEG_K;
            int c = nt * HID + wv * 16 + r;
            float s0 = Wih[c * 2 + 0] * gs;
            float s1 = Wih[c * 2 + 1] * gs;
            short8 tt;
#pragma unroll
            for (int j = 0; j < 8; ++j) {
                float f = Whh[(size_t)c * HID + k0 + j] * gs
                        + s0 * wo0[j] + s1 * wo1[j];
                tt[j] = (short)f2bf(f);
            }
            bfrag[nt][kf] = tt;
        }
    }

// ---- macros ----
// gates with rolling 2-deep A-fragment buffer (8 VGPR instead of 16)
#define GATES(rb)                                                    \
    {                                                                \
        const f32x4 z4 = {0.f, 0.f, 0.f, 0.f};                       \
        short8 afa = hb[rb][r][kb];                                  \
        short8 afb = hb[rb][r][4 + kb];                              \
        _Pragma("unroll")                                            \
        for (int nt = 0; nt < 4; ++nt)                               \
            acc[nt] = __builtin_amdgcn_mfma_f32_16x16x32_bf16(       \
                afa, bfrag[nt][0], z4, 0, 0, 0);                     \
        afa = hb[rb][r][8 + kb];                                     \
        _Pragma("unroll")                                            \
        for (int nt = 0; nt < 4; ++nt)                               \
            acc[nt] = __builtin_amdgcn_mfma_f32_16x16x32_bf16(       \
                afb, bfrag[nt][1], acc[nt], 0, 0, 0);                \
        afb = hb[rb][r][12 + kb];                                    \
        _Pragma("unroll")                                            \
        for (int nt = 0; nt < 4; ++nt)                               \
            acc[nt] = __builtin_amdgcn_mfma_f32_16x16x32_bf16(       \
                afa, bfrag[nt][2], acc[nt], 0, 0, 0);                \
        _Pragma("unroll")                                            \
        for (int nt = 0; nt < 4; ++nt)                               \
            acc[nt] = __builtin_amdgcn_mfma_f32_16x16x32_bf16(       \
                afb, bfrag[nt][3], acc[nt], 0, 0, 0);                \
    }

// out projection, wave 0 only; reads its own A-fragments from LDS
#define OUT_TILE(rb, dst_expr)                                       \
    if (wv == 0) {                                                   \
        const f32x4 z4o = {0.f, 0.f, 0.f, 0.f};                      \
        short8 t0 = hb[rb][r][kb];                                   \
        f32x4 oacc = __builtin_amdgcn_mfma_f32_16x16x32_bf16(        \
            t0, outb_lds[0][lane], z4o, 0, 0, 0);                    \
        t0 = hb[rb][r][4 + kb];                                      \
        oacc = __builtin_amdgcn_mfma_f32_16x16x32_bf16(              \
            t0, outb_lds[1][lane], oacc, 0, 0, 0);                   \
        t0 = hb[rb][r][8 + kb];                                      \
        oacc = __builtin_amdgcn_mfma_f32_16x16x32_bf16(              \
            t0, outb_lds[2][lane], oacc, 0, 0, 0);                   \
        t0 = hb[rb][r][12 + kb];                                     \
        oacc = __builtin_amdgcn_mfma_f32_16x16x32_bf16(              \
            t0, outb_lds[3][lane], oacc, 0, 0, 0);                   \
        if (r < 2) {                                                 \
            const float bo = (r == 0) ? bout0 : bout1;               \
            _Pragma("unroll")                                        \
            for (int q = 0; q < 4; ++q)                              \
                (dst_expr)[kb * 4 + q][r] = oacc[q] + bo;            \
        }                                                            \
    }

// step-0 exact correction; Wih/obs reloaded from global (L2-hot, once/tile)
#define CORR()                                                       \
    {                                                                \
        float dx0[4], dx1[4];                                        \
        _Pragma("unroll")                                            \
        for (int q = 0; q < 4; ++q) {                                \
            int ag = A0 + kb * 4 + q;                                \
            dx0[q] = obs[((size_t)(OBS - 1) * N_AGENTS + ag) * 2 + 0] - xt[kb * 4 + q][0]; \
            dx1[q] = obs[((size_t)(OBS - 1) * N_AGENTS + ag) * 2 + 1] - xt[kb * 4 + q][1]; \
        }                                                            \
        _Pragma("unroll")                                            \
        for (int nt = 0; nt < 4; ++nt) {                             \
            const float gs = (nt == 2) ? NEG_2K : NEG_K;             \
            int c = nt * HID + wv * 16 + r;                          \
            float w0s = Wih[c * 2 + 0] * gs;                         \
            float w1s = Wih[c * 2 + 1] * gs;                         \
            _Pragma("unroll")                                        \
            for (int q = 0; q < 4; ++q)                              \
                acc[nt][q] += dx0[q] * w0s + dx1[q] * w1s;           \
        }                                                            \
    }

// packed pair-cell (q pair), 14 trans / 2 cells, beff in-cell
#define CELLP(qa, qb)                                                \
    {                                                                \
        f32x2 Ei = {bexp2(acc[0][qa] + beff[0]), bexp2(acc[0][qb] + beff[0])}; \
        f32x2 Ef = {bexp2(acc[1][qa] + beff[1]), bexp2(acc[1][qb] + beff[1])}; \
        f32x2 Gg = {bexp2(acc[2][qa] + beff[2]), bexp2(acc[2][qb] + beff[2])}; \
        f32x2 Eo = {bexp2(acc[3][qa] + beff[3]), bexp2(acc[3][qb] + beff[3])}; \
        f32x2 c2 = {cf[qa], cf[qb]};                                 \
        f32x2 t1 = 1.0f + Ei;                                        \
        f32x2 t2 = 1.0f + Gg;                                        \
        f32x2 t3 = 1.0f + Ef;                                        \
        f32x2 t12 = t1 * t2;                                         \
        f32x2 num = t12 * c2 + t3 * (1.0f - Gg);                     \
        f32x2 den = t12 * t3;                                        \
        f32x2 R1 = {brcp(den.x), brcp(den.y)};                       \
        f32x2 cn = num * R1;                                         \
        cf[qa] = cn.x; cf[qb] = cn.y;                                \
        f32x2 ga = NEG_2K * cn;                                      \
        f32x2 Gc = {bexp2(ga.x), bexp2(ga.y)};                       \
        f32x2 u1 = (1.0f + Eo) * (1.0f + Gc);                        \
        f32x2 R2 = {brcp(u1.x), brcp(u1.y)};                         \
        f32x2 hv = (1.0f - Gc) * R2;                                 \
        unsigned pk = cvtpk(hv.x, hv.y);                             \
        hbase[(kb * 4 + qa) * 136 + wv * 16 + r] = (u16)pk;          \
        hbase[(kb * 4 + qb) * 136 + wv * 16 + r] = (u16)(pk >> 16);  \
    }

#define ACTIV(wb)                                                    \
    {                                                                \
        u16* hbase = (u16*)&hb[wb][0][0];                            \
        CELLP(0, 1) CELLP(2, 3)                                      \
    }

#pragma unroll 1
    for (int t = 0; t < AG; ++t) {
        const int A0 = (blockIdx.x * AG + t) * 16;

        // cooperative h0 preload -> hb[1] (bf16), 16 rows x 128 cols, 512 threads
        {
            int row = tid >> 5;            // 16 rows, 32 threads/row
            int c4  = (tid & 31) * 4;
            const float* hp = h0g + (size_t)(A0 + row) * HID + c4;
            f32x4 v = *(const f32x4*)hp;
            unsigned* dst = (unsigned*)&hb[1][row][0] + (tid & 31) * 2;
            dst[0] = cvtpk(v[0], v[1]);
            dst[1] = cvtpk(v[2], v[3]);
        }
        f32x4 cf = {0.f, 0.f, 0.f, 0.f};
        f32x4 acc[4];
        __syncthreads();

        // ---------------- step 0 ----------------
        GATES(1)
        OUT_TILE(1, xt)
        __syncthreads();   // x~0 visible
        CORR()
        ACTIV(0)
        __syncthreads();

        // ---------------- steps 1..11 ----------------
#pragma unroll 1
        for (int s = 1; s < FUT; ++s) {
            const int rb = (s - 1) & 1;
            GATES(rb)
            OUT_TILE(rb, ot[s - 1])
            ACTIV(s & 1)
            __syncthreads();
        }

        // ---------------- step 12: out only ----------------
        OUT_TILE(1, ot[FUT - 1])
        __syncthreads();

        // ---------------- coalesced flush: 384 floats ----------------
        if (tid < FUT * 32) {
            const float* otf = &ot[0][0][0];
            dout[((size_t)(tid >> 5) * N_AGENTS + A0) * 2 + (tid & 31)] = otf[tid];
        }
        // next ot write (s=1 OUT of next tile) is >=2 barriers away — safe
    }
#undef GATES
#undef OUT_TILE
#undef CORR
#undef CELLP
#undef ACTIV
}

extern "C" void kernel_launch(void* const* d_in, const int* in_sizes, int n_in,
                              void* d_out, int out_size, void* d_ws, size_t ws_size,
                              hipStream_t stream) {
    const float* obs  = (const float*)d_in[0];
    // d_in[1] (fut_traj_rel) is unused by the reference
    const float* h0   = (const float*)d_in[2];
    const float* Wih  = (const float*)d_in[3];
    const float* Whh  = (const float*)d_in[4];
    const float* bih  = (const float*)d_in[5];
    const float* bhh  = (const float*)d_in[6];
    const float* Wout = (const float*)d_in[7];
    const float* bo   = (const float*)d_in[8];
    float* out = (float*)d_out;

    dim3 grid(N_AGENTS / (AG * 16));   // 1024 blocks of 512 threads
    lstm_dec_kernel<<<grid, 512, 0, stream>>>(obs, h0, Wih, Whh, bih, bhh, Wout, bo, out);
}

// Round 13
// 321.890 us; speedup vs baseline: 1.1752x; 1.1752x over previous
//
#include <hip/hip_runtime.h>

typedef unsigned short u16;
typedef __attribute__((ext_vector_type(8))) short short8;
typedef __attribute__((ext_vector_type(4))) float f32x4;
typedef __attribute__((ext_vector_type(2))) float f32x2;

#define N_AGENTS 131072
#define HID 128
#define FUT 12
#define OBS 8

constexpr int AG = 16;             // 32-agent pair-tiles per block -> 512 agents/block
#define NEG_K  (-1.4426950408889634f)   // -log2(e)
#define NEG_2K (-2.8853900817779268f)   // -2*log2(e)

__device__ __forceinline__ u16 f2bf(float f) {   // RNE (setup only)
    union { float f; unsigned int i; } v; v.f = f;
    unsigned int u = v.i;
    return (u16)((u + 0x7fffu + ((u >> 16) & 1u)) >> 16);
}
__device__ __forceinline__ float bexp2(float x) {
#if __has_builtin(__builtin_amdgcn_exp2f)
    return __builtin_amdgcn_exp2f(x);
#else
    float r; asm("v_exp_f32 %0, %1" : "=v"(r) : "v"(x)); return r;
#endif
}
__device__ __forceinline__ float brcp(float x) {
#if __has_builtin(__builtin_amdgcn_rcpf)
    return __builtin_amdgcn_rcpf(x);
#else
    float r; asm("v_rcp_f32 %0, %1" : "=v"(r) : "v"(x)); return r;
#endif
}
__device__ __forceinline__ unsigned cvtpk(float lo, float hi) {  // 2x f32 -> packed bf16 (RNE)
    unsigned r; asm("v_cvt_pk_bf16_f32 %0, %1, %2" : "=v"(r) : "v"(lo), "v"(hi)); return r;
}

__launch_bounds__(1024, 4)
__global__ void lstm_dec_kernel(const float* __restrict__ obs,
                                const float* __restrict__ h0g,
                                const float* __restrict__ Wih,
                                const float* __restrict__ Whh,
                                const float* __restrict__ bih,
                                const float* __restrict__ bhh,
                                const float* __restrict__ Wout,
                                const float* __restrict__ bout,
                                float* __restrict__ dout)
{
    __shared__ short8 wB[32][4][64];      // 128 KB: W_eff B-fragments [ct][kf][lane]
    __shared__ short8 hb[2][32][17];      // 17 KB: h double-buffer, 272B rows
    __shared__ short8 outb_lds[4][64];    // 4 KB: W_out B-fragments
    __shared__ float  xt[32][2];
    __shared__ float  ot[FUT][32][2];     // 3 KB staged outputs

    const int tid  = threadIdx.x;
    const int lane = tid & 63;
    const int wv   = tid >> 6;      // wave 0..15
    const int at   = wv & 1;        // agent sub-tile (0: rows 0-15, 1: rows 16-31)
    const int hs   = wv >> 1;       // hidden slice 0..7 -> cols [16*hs, 16*hs+16)
    const int r    = lane & 15;
    const int kb   = lane >> 4;

    const float bout0 = bout[0];
    const float bout1 = bout[1];
    const float bo_sc = (r == 0) ? bout0 : ((r == 1) ? bout1 : 0.0f);
    const f32x4 oInit = {bo_sc, bo_sc, bo_sc, bo_sc};

    // scaled effective bias (added in-cell): col c = nt*128 + hs*16 + r
    float beff[4];
#pragma unroll
    for (int nt = 0; nt < 4; ++nt) {
        const float gs = (nt == 2) ? NEG_2K : NEG_K;
        int c = nt * HID + hs * 16 + r;
        float w0 = Wih[c * 2 + 0];
        float w1 = Wih[c * 2 + 1];
        beff[nt] = (bih[c] + bhh[c] + w0 * bout0 + w1 * bout1) * gs;
    }

    // build W_eff = (W_hh + W_ih @ W_out) * gsc fragments into LDS.
    // waves with at==0 build ct = nt*8+hs for all kf (8 waves x 16 frags = 128)
    if (at == 0) {
#pragma unroll
        for (int kf = 0; kf < 4; ++kf) {
            const int k0 = kf * 32 + kb * 8;
            float wo0[8], wo1[8];
#pragma unroll
            for (int j = 0; j < 8; ++j) {
                wo0[j] = Wout[0 * HID + k0 + j];
                wo1[j] = Wout[1 * HID + k0 + j];
            }
#pragma unroll
            for (int nt = 0; nt < 4; ++nt) {
                const float gs = (nt == 2) ? NEG_2K : NEG_K;
                int c = nt * HID + hs * 16 + r;
                float s0 = Wih[c * 2 + 0] * gs;
                float s1 = Wih[c * 2 + 1] * gs;
                short8 tt;
#pragma unroll
                for (int j = 0; j < 8; ++j) {
                    float f = Whh[(size_t)c * HID + k0 + j] * gs
                            + s0 * wo0[j] + s1 * wo1[j];
                    tt[j] = (short)f2bf(f);
                }
                wB[nt * 8 + hs][kf][lane] = tt;
            }
        }
    }
    if (wv == 1) {   // out-projection B-frags (lane-dependent only)
#pragma unroll
        for (int kf = 0; kf < 4; ++kf) {
            const int k0 = kf * 32 + kb * 8;
            short8 ob;
#pragma unroll
            for (int j = 0; j < 8; ++j) {
                float sel = (r == 0) ? Wout[k0 + j]
                          : ((r == 1) ? Wout[HID + k0 + j] : 0.0f);
                ob[j] = (short)f2bf(sel);
            }
            outb_lds[kf][lane] = ob;
        }
    }

// ---- macros ----
#define GATES(rb)                                                    \
    _Pragma("unroll")                                                \
    for (int kf = 0; kf < 4; ++kf)                                   \
        af[kf] = hb[rb][at * 16 + r][kf * 4 + kb];                   \
    {                                                                \
        const f32x4 z4 = {0.f, 0.f, 0.f, 0.f};                       \
        _Pragma("unroll")                                            \
        for (int nt = 0; nt < 4; ++nt)                               \
            acc[nt] = __builtin_amdgcn_mfma_f32_16x16x32_bf16(       \
                af[0], wB[nt * 8 + hs][0][lane], z4, 0, 0, 0);       \
        _Pragma("unroll")                                            \
        for (int kf = 1; kf < 4; ++kf)                               \
            _Pragma("unroll")                                        \
            for (int nt = 0; nt < 4; ++nt)                           \
                acc[nt] = __builtin_amdgcn_mfma_f32_16x16x32_bf16(   \
                    af[kf], wB[nt * 8 + hs][kf][lane], acc[nt], 0, 0, 0); \
    }

// out projection: wave 0 covers rows 0-15 (its at=0), wave 1 rows 16-31 (at=1);
// reads hb directly so it also works in the GATES-free step-12 phase
#define OUT_TILE(rb, dst_expr)                                       \
    if (wv < 2) {                                                    \
        short8 t0 = hb[rb][at * 16 + r][kb];                         \
        f32x4 oacc = __builtin_amdgcn_mfma_f32_16x16x32_bf16(        \
            t0, outb_lds[0][lane], oInit, 0, 0, 0);                  \
        t0 = hb[rb][at * 16 + r][4 + kb];                            \
        oacc = __builtin_amdgcn_mfma_f32_16x16x32_bf16(              \
            t0, outb_lds[1][lane], oacc, 0, 0, 0);                   \
        t0 = hb[rb][at * 16 + r][8 + kb];                            \
        oacc = __builtin_amdgcn_mfma_f32_16x16x32_bf16(              \
            t0, outb_lds[2][lane], oacc, 0, 0, 0);                   \
        t0 = hb[rb][at * 16 + r][12 + kb];                           \
        oacc = __builtin_amdgcn_mfma_f32_16x16x32_bf16(              \
            t0, outb_lds[3][lane], oacc, 0, 0, 0);                   \
        if (r < 2) {                                                 \
            _Pragma("unroll")                                        \
            for (int q = 0; q < 4; ++q)                              \
                (dst_expr)[at * 16 + kb * 4 + q][r] = oacc[q];       \
        }                                                            \
    }

// step-0 exact correction for this wave's agent sub-tile (obs/Wih L2-hot)
#define CORR()                                                       \
    {                                                                \
        float dx0[4], dx1[4];                                        \
        _Pragma("unroll")                                            \
        for (int q = 0; q < 4; ++q) {                                \
            int a  = at * 16 + kb * 4 + q;                           \
            int ag = A0 + a;                                         \
            dx0[q] = obs[((size_t)(OBS - 1) * N_AGENTS + ag) * 2 + 0] - xt[a][0]; \
            dx1[q] = obs[((size_t)(OBS - 1) * N_AGENTS + ag) * 2 + 1] - xt[a][1]; \
        }                                                            \
        _Pragma("unroll")                                            \
        for (int nt = 0; nt < 4; ++nt) {                             \
            const float gs = (nt == 2) ? NEG_2K : NEG_K;             \
            int c = nt * HID + hs * 16 + r;                          \
            float w0s = Wih[c * 2 + 0] * gs;                         \
            float w1s = Wih[c * 2 + 1] * gs;                         \
            _Pragma("unroll")                                        \
            for (int q = 0; q < 4; ++q)                              \
                acc[nt][q] += dx0[q] * w0s + dx1[q] * w1s;           \
        }                                                            \
    }

// packed pair-cell (q pair), 14 trans / 2 cells, beff in-cell (math = R7..R12)
#define CELLP(qa, qb)                                                \
    {                                                                \
        f32x2 Ei = {bexp2(acc[0][qa] + beff[0]), bexp2(acc[0][qb] + beff[0])}; \
        f32x2 Ef = {bexp2(acc[1][qa] + beff[1]), bexp2(acc[1][qb] + beff[1])}; \
        f32x2 Gg = {bexp2(acc[2][qa] + beff[2]), bexp2(acc[2][qb] + beff[2])}; \
        f32x2 Eo = {bexp2(acc[3][qa] + beff[3]), bexp2(acc[3][qb] + beff[3])}; \
        f32x2 c2 = {cf[qa], cf[qb]};                                 \
        f32x2 t1 = 1.0f + Ei;                                        \
        f32x2 t2 = 1.0f + Gg;                                        \
        f32x2 t3 = 1.0f + Ef;                                        \
        f32x2 t12 = t1 * t2;                                         \
        f32x2 num = t12 * c2 + t3 * (1.0f - Gg);                     \
        f32x2 den = t12 * t3;                                        \
        f32x2 R1 = {brcp(den.x), brcp(den.y)};                       \
        f32x2 cn = num * R1;                                         \
        cf[qa] = cn.x; cf[qb] = cn.y;                                \
        f32x2 ga = NEG_2K * cn;                                      \
        f32x2 Gc = {bexp2(ga.x), bexp2(ga.y)};                       \
        f32x2 u1 = (1.0f + Eo) * (1.0f + Gc);                        \
        f32x2 R2 = {brcp(u1.x), brcp(u1.y)};                         \
        f32x2 hv = (1.0f - Gc) * R2;                                 \
        unsigned pk = cvtpk(hv.x, hv.y);                             \
        hbase[(at * 16 + kb * 4 + qa) * 136 + hs * 16 + r] = (u16)pk; \
        hbase[(at * 16 + kb * 4 + qb) * 136 + hs * 16 + r] = (u16)(pk >> 16); \
    }

#define ACTIV(wb)                                                    \
    {                                                                \
        u16* hbase = (u16*)&hb[wb][0][0];                            \
        CELLP(0, 1) CELLP(2, 3)                                      \
    }

#pragma unroll 1
    for (int t = 0; t < AG; ++t) {
        const int A0 = (blockIdx.x * AG + t) * 32;

        // cooperative h0 preload -> hb[1]: 32 rows, 32 threads/row, 4 f32 each
        {
            int row = tid >> 5;
            int c4  = (tid & 31) * 4;
            const float* hp = h0g + (size_t)(A0 + row) * HID + c4;
            f32x4 v = *(const f32x4*)hp;
            unsigned* dst = (unsigned*)&hb[1][row][0] + (tid & 31) * 2;
            dst[0] = cvtpk(v[0], v[1]);
            dst[1] = cvtpk(v[2], v[3]);
        }
        f32x4 cf = {0.f, 0.f, 0.f, 0.f};
        f32x4 acc[4];
        short8 af[4];
        __syncthreads();

        // ---------------- step 0 ----------------
        GATES(1)
        OUT_TILE(1, xt)
        __syncthreads();   // x~0 visible
        CORR()
        ACTIV(0)
        __syncthreads();

        // ---------------- steps 1..11 ----------------
#pragma unroll 1
        for (int s = 1; s < FUT; ++s) {
            const int rb = (s - 1) & 1;
            GATES(rb)
            OUT_TILE(rb, ot[s - 1])
            ACTIV(s & 1)
            __syncthreads();
        }

        // ---------------- step 12: out only ----------------
        OUT_TILE(1, ot[FUT - 1])
        __syncthreads();

        // ---------------- coalesced flush: 768 floats ----------------
        if (tid < FUT * 64) {
            const float* otf = &ot[0][0][0];
            dout[((size_t)(tid >> 6) * N_AGENTS + A0) * 2 + (tid & 63)] = otf[tid];
        }
        // next preload writes hb[1] only after the loop-top barrier;
        // next ot write (s=1 of next tile) is >=2 barriers away — safe
    }
#undef GATES
#undef OUT_TILE
#undef CORR
#undef CELLP
#undef ACTIV
}

extern "C" void kernel_launch(void* const* d_in, const int* in_sizes, int n_in,
                              void* d_out, int out_size, void* d_ws, size_t ws_size,
                              hipStream_t stream) {
    const float* obs  = (const float*)d_in[0];
    // d_in[1] (fut_traj_rel) is unused by the reference
    const float* h0   = (const float*)d_in[2];
    const float* Wih  = (const float*)d_in[3];
    const float* Whh  = (const float*)d_in[4];
    const float* bih  = (const float*)d_in[5];
    const float* bhh  = (const float*)d_in[6];
    const float* Wout = (const float*)d_in[7];
    const float* bo   = (const float*)d_in[8];
    float* out = (float*)d_out;

    dim3 grid(N_AGENTS / (AG * 32));   // 256 blocks of 1024 threads (1 per CU)
    lstm_dec_kernel<<<grid, 1024, 0, stream>>>(obs, h0, Wih, Whh, bih, bhh, Wout, bo, out);
}

// Round 14
// 303.090 us; speedup vs baseline: 1.2481x; 1.0620x over previous
//
#include <hip/hip_runtime.h>

typedef unsigned short u16;
typedef __attribute__((ext_vector_type(8))) short short8;
typedef __attribute__((ext_vector_type(4))) float f32x4;
typedef __attribute__((ext_vector_type(2))) float f32x2;

#define N_AGENTS 131072
#define HID 128
#define FUT 12
#define OBS 8

constexpr int AG = 8;              // 64-agent quad-tiles per block -> 512 agents/block
#define NEG_K  (-1.4426950408889634f)   // -log2(e)
#define NEG_2K (-2.8853900817779268f)   // -2*log2(e)

__device__ __forceinline__ u16 f2bf(float f) {   // RNE (setup only)
    union { float f; unsigned int i; } v; v.f = f;
    unsigned int u = v.i;
    return (u16)((u + 0x7fffu + ((u >> 16) & 1u)) >> 16);
}
__device__ __forceinline__ float bexp2(float x) {
#if __has_builtin(__builtin_amdgcn_exp2f)
    return __builtin_amdgcn_exp2f(x);
#else
    float r; asm("v_exp_f32 %0, %1" : "=v"(r) : "v"(x)); return r;
#endif
}
__device__ __forceinline__ float brcp(float x) {
#if __has_builtin(__builtin_amdgcn_rcpf)
    return __builtin_amdgcn_rcpf(x);
#else
    float r; asm("v_rcp_f32 %0, %1" : "=v"(r) : "v"(x)); return r;
#endif
}
__device__ __forceinline__ unsigned cvtpk(float lo, float hi) {  // 2x f32 -> packed bf16 (RNE)
    unsigned r; asm("v_cvt_pk_bf16_f32 %0, %1, %2" : "=v"(r) : "v"(lo), "v"(hi)); return r;
}

__launch_bounds__(1024, 4)
__global__ void lstm_dec_kernel(const float* __restrict__ obs,
                                const float* __restrict__ h0g,
                                const float* __restrict__ Wih,
                                const float* __restrict__ Whh,
                                const float* __restrict__ bih,
                                const float* __restrict__ bhh,
                                const float* __restrict__ Wout,
                                const float* __restrict__ bout,
                                float* __restrict__ dout)
{
    __shared__ short8 wB[32][4][64];      // 128 KB: W_eff B-frags, ct = nt*8 + hsl
    __shared__ short8 hb[64][17];         // 17 KB: h single buffer, 272B rows
    __shared__ short8 outb_lds[4][64];    // 4 KB: W_out B-frags
    __shared__ float  xt[64][2];          // 0.5 KB
    __shared__ float  ot[FUT][64][2];     // 6 KB staged outputs

    const int tid  = threadIdx.x;
    const int lane = tid & 63;
    const int wv   = tid >> 6;      // wave 0..15
    const int hs   = wv & 7;        // hidden slice: gate cols [16*hs, 16*hs+16)
    const int ap   = wv >> 3;       // agent pair: tiles {2ap, 2ap+1}
    const int T0   = ap * 2;
    const int T1   = ap * 2 + 1;
    const int r    = lane & 15;
    const int kb   = lane >> 4;

    const float bout0 = bout[0];
    const float bout1 = bout[1];
    const float bo_sc = (r == 0) ? bout0 : ((r == 1) ? bout1 : 0.0f);
    const f32x4 oInit = {bo_sc, bo_sc, bo_sc, bo_sc};

    // scaled effective bias (in-cell): col c = nt*128 + hs*16 + r
    float beff[4];
#pragma unroll
    for (int nt = 0; nt < 4; ++nt) {
        const float gs = (nt == 2) ? NEG_2K : NEG_K;
        int c = nt * HID + hs * 16 + r;
        beff[nt] = (bih[c] + bhh[c] + Wih[c * 2 + 0] * bout0 + Wih[c * 2 + 1] * bout1) * gs;
    }

    // build W_eff = (W_hh + W_ih @ W_out) * gsc into LDS: wave wv builds ct = 2wv, 2wv+1
#pragma unroll
    for (int ci = 0; ci < 2; ++ci) {
        const int ct  = wv * 2 + ci;
        const int nt  = ct >> 3;
        const float gs = (nt == 2) ? NEG_2K : NEG_K;
        const int c   = nt * HID + (ct & 7) * 16 + r;
        const float s0 = Wih[c * 2 + 0] * gs;
        const float s1 = Wih[c * 2 + 1] * gs;
#pragma unroll
        for (int kf = 0; kf < 4; ++kf) {
            const int k0 = kf * 32 + kb * 8;
            short8 tt;
#pragma unroll
            for (int j = 0; j < 8; ++j) {
                float f = Whh[(size_t)c * HID + k0 + j] * gs
                        + s0 * Wout[k0 + j] + s1 * Wout[HID + k0 + j];
                tt[j] = (short)f2bf(f);
            }
            wB[ct][kf][lane] = tt;
        }
    }
    if (wv == 15) {   // out-projection B-frags
#pragma unroll
        for (int kf = 0; kf < 4; ++kf) {
            const int k0 = kf * 32 + kb * 8;
            short8 ob;
#pragma unroll
            for (int j = 0; j < 8; ++j) {
                float sel = (r == 0) ? Wout[k0 + j]
                          : ((r == 1) ? Wout[HID + k0 + j] : 0.0f);
                ob[j] = (short)f2bf(sel);
            }
            outb_lds[kf][lane] = ob;
        }
    }

// ---- macros ----
// gate GEMM for both tiles; each B-frag read feeds 2 MFMAs
#define GATES()                                                      \
    {                                                                \
        short8 a0[4], a1[4];                                         \
        _Pragma("unroll")                                            \
        for (int kf = 0; kf < 4; ++kf) {                             \
            a0[kf] = hb[T0 * 16 + r][kf * 4 + kb];                   \
            a1[kf] = hb[T1 * 16 + r][kf * 4 + kb];                   \
        }                                                            \
        const f32x4 z4 = {0.f, 0.f, 0.f, 0.f};                       \
        _Pragma("unroll")                                            \
        for (int nt = 0; nt < 4; ++nt) {                             \
            short8 b = wB[nt * 8 + hs][0][lane];                     \
            accA[nt] = __builtin_amdgcn_mfma_f32_16x16x32_bf16(a0[0], b, z4, 0, 0, 0); \
            accB[nt] = __builtin_amdgcn_mfma_f32_16x16x32_bf16(a1[0], b, z4, 0, 0, 0); \
        }                                                            \
        _Pragma("unroll")                                            \
        for (int kf = 1; kf < 4; ++kf)                               \
            _Pragma("unroll")                                        \
            for (int nt = 0; nt < 4; ++nt) {                         \
                short8 b = wB[nt * 8 + hs][kf][lane];                \
                accA[nt] = __builtin_amdgcn_mfma_f32_16x16x32_bf16(a0[kf], b, accA[nt], 0, 0, 0); \
                accB[nt] = __builtin_amdgcn_mfma_f32_16x16x32_bf16(a1[kf], b, accB[nt], 0, 0, 0); \
            }                                                        \
    }

// out projection: waves 0..3 cover tile wv (rows wv*16..+16)
#define OUT_TILE(dst_expr)                                           \
    if (wv < 4) {                                                    \
        short8 t0 = hb[wv * 16 + r][kb];                             \
        f32x4 oacc = __builtin_amdgcn_mfma_f32_16x16x32_bf16(        \
            t0, outb_lds[0][lane], oInit, 0, 0, 0);                  \
        t0 = hb[wv * 16 + r][4 + kb];                                \
        oacc = __builtin_amdgcn_mfma_f32_16x16x32_bf16(              \
            t0, outb_lds[1][lane], oacc, 0, 0, 0);                   \
        t0 = hb[wv * 16 + r][8 + kb];                                \
        oacc = __builtin_amdgcn_mfma_f32_16x16x32_bf16(              \
            t0, outb_lds[2][lane], oacc, 0, 0, 0);                   \
        t0 = hb[wv * 16 + r][12 + kb];                               \
        oacc = __builtin_amdgcn_mfma_f32_16x16x32_bf16(              \
            t0, outb_lds[3][lane], oacc, 0, 0, 0);                   \
        if (r < 2) {                                                 \
            _Pragma("unroll")                                        \
            for (int q = 0; q < 4; ++q)                              \
                (dst_expr)[wv * 16 + kb * 4 + q][r] = oacc[q];       \
        }                                                            \
    }

// step-0 exact correction for both tiles (obs/Wih L2-hot, once per quad-tile)
#define CORR()                                                       \
    {                                                                \
        float dA0[4], dA1[4], dB0[4], dB1[4];                        \
        _Pragma("unroll")                                            \
        for (int q = 0; q < 4; ++q) {                                \
            int aA = T0 * 16 + kb * 4 + q;                           \
            int aB = T1 * 16 + kb * 4 + q;                           \
            dA0[q] = obs[((size_t)(OBS - 1) * N_AGENTS + A0 + aA) * 2 + 0] - xt[aA][0]; \
            dA1[q] = obs[((size_t)(OBS - 1) * N_AGENTS + A0 + aA) * 2 + 1] - xt[aA][1]; \
            dB0[q] = obs[((size_t)(OBS - 1) * N_AGENTS + A0 + aB) * 2 + 0] - xt[aB][0]; \
            dB1[q] = obs[((size_t)(OBS - 1) * N_AGENTS + A0 + aB) * 2 + 1] - xt[aB][1]; \
        }                                                            \
        _Pragma("unroll")                                            \
        for (int nt = 0; nt < 4; ++nt) {                             \
            const float gs = (nt == 2) ? NEG_2K : NEG_K;             \
            int c = nt * HID + hs * 16 + r;                          \
            float w0s = Wih[c * 2 + 0] * gs;                         \
            float w1s = Wih[c * 2 + 1] * gs;                         \
            _Pragma("unroll")                                        \
            for (int q = 0; q < 4; ++q) {                            \
                accA[nt][q] += dA0[q] * w0s + dA1[q] * w1s;          \
                accB[nt][q] += dB0[q] * w0s + dB1[q] * w1s;          \
            }                                                        \
        }                                                            \
    }

// packed pair-cell (q pair within one tile), math identical to R7..R13
#define CELLP(acc, cf, qa, qb, T)                                    \
    {                                                                \
        f32x2 Ei = {bexp2(acc[0][qa] + beff[0]), bexp2(acc[0][qb] + beff[0])}; \
        f32x2 Ef = {bexp2(acc[1][qa] + beff[1]), bexp2(acc[1][qb] + beff[1])}; \
        f32x2 Gg = {bexp2(acc[2][qa] + beff[2]), bexp2(acc[2][qb] + beff[2])}; \
        f32x2 Eo = {bexp2(acc[3][qa] + beff[3]), bexp2(acc[3][qb] + beff[3])}; \
        f32x2 c2 = {cf[qa], cf[qb]};                                 \
        f32x2 t1 = 1.0f + Ei;                                        \
        f32x2 t2 = 1.0f + Gg;                                        \
        f32x2 t3 = 1.0f + Ef;                                        \
        f32x2 t12 = t1 * t2;                                         \
        f32x2 num = t12 * c2 + t3 * (1.0f - Gg);                     \
        f32x2 den = t12 * t3;                                        \
        f32x2 R1 = {brcp(den.x), brcp(den.y)};                       \
        f32x2 cn = num * R1;                                         \
        cf[qa] = cn.x; cf[qb] = cn.y;                                \
        f32x2 ga = NEG_2K * cn;                                      \
        f32x2 Gc = {bexp2(ga.x), bexp2(ga.y)};                       \
        f32x2 u1 = (1.0f + Eo) * (1.0f + Gc);                        \
        f32x2 R2 = {brcp(u1.x), brcp(u1.y)};                         \
        f32x2 hv = (1.0f - Gc) * R2;                                 \
        unsigned pk = cvtpk(hv.x, hv.y);                             \
        hbase[((T) * 16 + kb * 4 + qa) * 136 + hcol] = (u16)pk;      \
        hbase[((T) * 16 + kb * 4 + qb) * 136 + hcol] = (u16)(pk >> 16); \
    }

#define ACTIV()                                                      \
    {                                                                \
        u16* hbase = (u16*)&hb[0][0];                                \
        const int hcol = hs * 16 + r;                                \
        CELLP(accA, cfA, 0, 1, T0) CELLP(accA, cfA, 2, 3, T0)        \
        CELLP(accB, cfB, 0, 1, T1) CELLP(accB, cfB, 2, 3, T1)        \
    }

#pragma unroll 1
    for (int t = 0; t < AG; ++t) {
        const int A0 = (blockIdx.x * AG + t) * 64;

        // cooperative h0 preload -> hb: 64 rows, 16 threads/row, 8 f32 each
        {
            int row = tid >> 4;
            int c8  = (tid & 15) * 8;
            const float* hp = h0g + (size_t)(A0 + row) * HID + c8;
            f32x4 lo = *(const f32x4*)hp;
            f32x4 hi = *(const f32x4*)(hp + 4);
            short8 a;
            unsigned* apk = (unsigned*)&a;
            apk[0] = cvtpk(lo[0], lo[1]);
            apk[1] = cvtpk(lo[2], lo[3]);
            apk[2] = cvtpk(hi[0], hi[1]);
            apk[3] = cvtpk(hi[2], hi[3]);
            hb[row][tid & 15] = a;
        }
        f32x4 cfA = {0.f, 0.f, 0.f, 0.f};
        f32x4 cfB = {0.f, 0.f, 0.f, 0.f};
        f32x4 accA[4], accB[4];
        __syncthreads();

        // ---------------- step 0 ----------------
        GATES()
        OUT_TILE(xt)
        __syncthreads();   // x~0 visible; all h0 reads done
        CORR()
        ACTIV()
        __syncthreads();   // h(0) visible

        // ---------------- steps 1..11 ----------------
#pragma unroll 1
        for (int s = 1; s < FUT; ++s) {
            GATES()
            OUT_TILE(ot[s - 1])
            __syncthreads();   // all h(s-1) reads done
            ACTIV()
            __syncthreads();   // h(s) visible
        }

        // ---------------- step 12: out only ----------------
        OUT_TILE(ot[FUT - 1])
        __syncthreads();       // ot complete; hb reads done

        // ---------------- coalesced flush: 1536 floats ----------------
        {
            const float* otf = &ot[0][0][0];
            dout[((size_t)(tid >> 7) * N_AGENTS + A0) * 2 + (tid & 127)] = otf[tid];
            int idx = tid + 1024;
            if (idx < FUT * 128)
                dout[((size_t)(idx >> 7) * N_AGENTS + A0) * 2 + (idx & 127)] = otf[idx];
        }
        // next preload writes hb only after this tile's step-12 barrier;
        // next ot write (s=1 of next tile) is >=3 barriers away — safe
    }
#undef GATES
#undef OUT_TILE
#undef CORR
#undef CELLP
#undef ACTIV
}

extern "C" void kernel_launch(void* const* d_in, const int* in_sizes, int n_in,
                              void* d_out, int out_size, void* d_ws, size_t ws_size,
                              hipStream_t stream) {
    const float* obs  = (const float*)d_in[0];
    // d_in[1] (fut_traj_rel) is unused by the reference
    const float* h0   = (const float*)d_in[2];
    const float* Wih  = (const float*)d_in[3];
    const float* Whh  = (const float*)d_in[4];
    const float* bih  = (const float*)d_in[5];
    const float* bhh  = (const float*)d_in[6];
    const float* Wout = (const float*)d_in[7];
    const float* bo   = (const float*)d_in[8];
    float* out = (float*)d_out;

    dim3 grid(N_AGENTS / (AG * 64));   // 256 blocks of 1024 threads (1 per CU)
    lstm_dec_kernel<<<grid, 1024, 0, stream>>>(obs, h0, Wih, Whh, bih, bhh, Wout, bo, out);
}